// Round 8
// baseline (73.198 us; speedup 1.0000x reference)
//
#include <hip/hip_runtime.h>
#include <math.h>

#define H 8
#define B 64
#define D 512
#define HBD (H * B * D)
#define EPS 1e-8f
#define INV_SQRT_D 0.04419417382415922f   // 1/sqrt(512)
#define LN2 0.6931471805599453f
#define EPS_LN2 6.931471805599453e-9f     // EPS * ln(2)
#define CUTOFF 34.0f                      // drop weights below 2^-34
#define TMAX_FALLBACK 36.0f               // flat softmax -> exact full scan
#define WIN 16                            // fixed half-window around insertion pt

__device__ __forceinline__ float fast_rcp(float x) { return __builtin_amdgcn_rcpf(x); }
__device__ __forceinline__ float fast_exp2(float x) { return __builtin_amdgcn_exp2f(x); }

// ---------------------------------------------------------------------------
// Kernel 1: per (h,b), compute q,v and bitonic-sort by q (register/shuffle),
// publish sorted arrays to ws planes 0 (q) and 1 (v).
// ---------------------------------------------------------------------------
__global__ __launch_bounds__(512, 2) void sort_qv(
    const float* __restrict__ x,
    const float* __restrict__ Wq, const float* __restrict__ bq,
    const float* __restrict__ Wv, const float* __restrict__ bv,
    float* __restrict__ ws)
{
    const int hb = blockIdx.x;          // 0..H*B-1
    const int h = hb >> 6;              // B == 64
    const int b = hb & 63;
    const int t = threadIdx.x;

    __shared__ __align__(16) float qs[D];
    __shared__ __align__(16) float vs[D];

    const float xv = x[b * D + t];
    float q = Wq[h * D + t] * xv + bq[h * D + t];
    float v = Wv[h * D + t] * xv + bv[h * D + t];

    // Bitonic sort ascending by q, v payload: j<=32 via shfl, j>=64 via LDS
    for (int k = 2; k <= D; k <<= 1) {
        const bool up = ((t & k) == 0);
        for (int j = k >> 1; j > 0; j >>= 1) {
            float qp, vp;
            if (j >= 64) {
                qs[t] = q; vs[t] = v;
                __syncthreads();
                qp = qs[t ^ j]; vp = vs[t ^ j];
                __syncthreads();
            } else {
                qp = __shfl_xor(q, j, 64);
                vp = __shfl_xor(v, j, 64);
            }
            const bool keepmin = (((t & j) == 0) == up);
            const bool take = keepmin ? (qp < q) : (qp > q);
            if (take) { q = qp; v = vp; }
        }
    }

    ws[hb * D + t]       = q;   // sorted q plane
    ws[HBD + hb * D + t] = v;   // sorted v plane
}

// ---------------------------------------------------------------------------
// Kernel 2: 4 blocks per (h,b), 128 threads each (one row per thread).
// Stage sorted (q,v) L2->LDS coalesced; binary-search k_i; fixed-window
// accumulate (independent loads, no break); rare exact extensions.
// Writes attended rows to ws plane 2.
// ---------------------------------------------------------------------------
__global__ __launch_bounds__(128, 4) void attn_scan(
    const float* __restrict__ x,
    const float* __restrict__ Wk, const float* __restrict__ bk,
    const float* __restrict__ ws_in,   // planes 0,1
    float* __restrict__ ws_att)        // plane 2 base
{
    const int blk = blockIdx.x;         // 0..4*H*B-1
    const int hb = blk >> 2;
    const int chunk = blk & 3;
    const int h = hb >> 6;
    const int b = hb & 63;
    const int t = threadIdx.x;          // 0..127
    const int i = chunk * 128 + t;      // row

    __shared__ __align__(16) float qs[D];
    __shared__ __align__(16) float vs[D];

    // Stage sorted arrays: 128 threads x 1 float4 each per plane
    const float4* gq = reinterpret_cast<const float4*>(ws_in + (size_t)hb * D);
    const float4* gv = reinterpret_cast<const float4*>(ws_in + HBD + (size_t)hb * D);
    reinterpret_cast<float4*>(qs)[t] = gq[t];
    reinterpret_cast<float4*>(vs)[t] = gv[t];
    const float ki = Wk[h * D + i] * x[b * D + i] + bk[h * D + i];
    __syncthreads();

    // Binary search: p = count of qs[] < ki  (513 possible answers -> while loop)
    int lo = 0, hi = D;
    while (lo < hi) {
        const int mid = (lo + hi) >> 1;
        if (qs[mid] < ki) lo = mid + 1; else hi = mid;
    }
    const int p = lo;

    const float dlo = (p > 0) ? (ki - qs[p - 1]) : INFINITY;
    const float dhi = (p < D) ? (qs[p] - ki) : INFINITY;
    const float dmin = fmaxf(fminf(dlo, dhi), 0.f);
    const float tmax = fast_rcp(fmaf(dmin, LN2, EPS_LN2));

    float l = 0.f, a = 0.f;
    if (tmax < TMAX_FALLBACK) {
        // Flat softmax: exact full scan (correctness for arbitrary data)
        for (int s = 0; s < D; ++s) {
            const float d = fabsf(qs[s] - ki);
            const float e = fast_exp2(fast_rcp(fmaf(d, LN2, EPS_LN2)) - tmax);
            l += e; a = fmaf(e, vs[s], a);
        }
    } else {
        // Fixed window [p-WIN, p+WIN): independent loads, select-masked
        #pragma unroll 8
        for (int o = 0; o < 2 * WIN; ++o) {
            const int s = p - WIN + o;
            const bool valid = (s >= 0) && (s < D);
            const int sc = valid ? s : 0;
            const float d = fabsf(qs[sc] - ki);
            float e = fast_exp2(fast_rcp(fmaf(d, LN2, EPS_LN2)) - tmax);
            e = valid ? e : 0.f;
            l += e; a = fmaf(e, vs[sc], a);
        }
        // Exactness guards: extend beyond the window while still within rad
        const float rad = fast_rcp((tmax - CUTOFF) * LN2) * 1.001f;
        for (int s = p - WIN - 1; s >= 0; --s) {
            const float d = ki - qs[s];
            if (d > rad) break;
            const float e = fast_exp2(fast_rcp(fmaf(d, LN2, EPS_LN2)) - tmax);
            l += e; a = fmaf(e, vs[s], a);
        }
        for (int s = p + WIN; s < D; ++s) {
            const float d = qs[s] - ki;
            if (d > rad) break;
            const float e = fast_exp2(fast_rcp(fmaf(d, LN2, EPS_LN2)) - tmax);
            l += e; a = fmaf(e, vs[s], a);
        }
    }

    ws_att[hb * D + i] = a * fast_rcp(l) * INV_SQRT_D;
}

// out[b,i] = x[b,i] + sum_h att[h,b,i]  (deterministic h-sum)
__global__ __launch_bounds__(256) void reduce_h(
    const float* __restrict__ x, const float* __restrict__ att,
    float* __restrict__ out)
{
    const int i = blockIdx.x * 256 + threadIdx.x;   // 0..B*D-1
    float s = x[i];
    #pragma unroll
    for (int h = 0; h < H; ++h) s += att[h * (B * D) + i];
    out[i] = s;
}

// ---------------------------------------------------------------------------
// Fallback (ws too small): fully fused exact kernel.
// ---------------------------------------------------------------------------
__global__ __launch_bounds__(512) void attn_fused(
    const float* __restrict__ x,
    const float* __restrict__ Wq, const float* __restrict__ bq,
    const float* __restrict__ Wk, const float* __restrict__ bk,
    const float* __restrict__ Wv, const float* __restrict__ bv,
    float* __restrict__ out)
{
    const int b = blockIdx.x;
    const int t = threadIdx.x;

    __shared__ float qs[D];
    __shared__ float vs[D];

    const float xv = x[b * D + t];
    float total = 0.f;

    for (int h = 0; h < H; ++h) {
        __syncthreads();
        qs[t] = Wq[h * D + t] * xv + bq[h * D + t];
        vs[t] = Wv[h * D + t] * xv + bv[h * D + t];
        const float ki = Wk[h * D + t] * xv + bk[h * D + t];
        __syncthreads();

        const float4* q4 = reinterpret_cast<const float4*>(qs);
        const float4* v4 = reinterpret_cast<const float4*>(vs);

        float d0 = INFINITY, d1 = INFINITY, d2 = INFINITY, d3 = INFINITY;
        for (int j = 0; j < D / 4; ++j) {
            float4 qq = q4[j];
            d0 = fminf(d0, fabsf(qq.x - ki));
            d1 = fminf(d1, fabsf(qq.y - ki));
            d2 = fminf(d2, fabsf(qq.z - ki));
            d3 = fminf(d3, fabsf(qq.w - ki));
        }
        const float dmin = fminf(fminf(d0, d1), fminf(d2, d3));
        const float tmax = fast_rcp(fmaf(dmin, LN2, EPS_LN2));

        float l0 = 0.f, l1 = 0.f, l2 = 0.f, l3 = 0.f;
        float a0 = 0.f, a1 = 0.f, a2 = 0.f, a3 = 0.f;
        for (int j = 0; j < D / 4; ++j) {
            float4 qq = q4[j];
            float4 vv = v4[j];
            float e0 = fast_exp2(fast_rcp(fmaf(fabsf(qq.x - ki), LN2, EPS_LN2)) - tmax);
            float e1 = fast_exp2(fast_rcp(fmaf(fabsf(qq.y - ki), LN2, EPS_LN2)) - tmax);
            float e2 = fast_exp2(fast_rcp(fmaf(fabsf(qq.z - ki), LN2, EPS_LN2)) - tmax);
            float e3 = fast_exp2(fast_rcp(fmaf(fabsf(qq.w - ki), LN2, EPS_LN2)) - tmax);
            l0 += e0; a0 = fmaf(e0, vv.x, a0);
            l1 += e1; a1 = fmaf(e1, vv.y, a1);
            l2 += e2; a2 = fmaf(e2, vv.z, a2);
            l3 += e3; a3 = fmaf(e3, vv.w, a3);
        }
        const float l = (l0 + l1) + (l2 + l3);
        const float a = (a0 + a1) + (a2 + a3);
        total += a * fast_rcp(l) * INV_SQRT_D;
    }
    out[b * D + t] = xv + total;
}

extern "C" void kernel_launch(void* const* d_in, const int* in_sizes, int n_in,
                              void* d_out, int out_size, void* d_ws, size_t ws_size,
                              hipStream_t stream) {
    const float* x  = (const float*)d_in[0];
    const float* Wq = (const float*)d_in[1];
    const float* bq = (const float*)d_in[2];
    const float* Wk = (const float*)d_in[3];
    const float* bk = (const float*)d_in[4];
    const float* Wv = (const float*)d_in[5];
    const float* bv = (const float*)d_in[6];
    float* out = (float*)d_out;

    const size_t need = (size_t)3 * HBD * sizeof(float);   // 3 MB

    if (ws_size >= need) {
        float* ws = (float*)d_ws;
        sort_qv<<<H * B, 512, 0, stream>>>(x, Wq, bq, Wv, bv, ws);
        attn_scan<<<4 * H * B, 128, 0, stream>>>(x, Wk, bk, ws, ws + 2 * (size_t)HBD);
        reduce_h<<<(B * D) / 256, 256, 0, stream>>>(x, ws + 2 * (size_t)HBD, out);
    } else {
        attn_fused<<<B, 512, 0, stream>>>(x, Wq, bq, Wk, bk, Wv, bv, out);
    }
}

// Round 9
// 56.198 us; speedup vs baseline: 1.3025x; 1.3025x over previous
//
#include <hip/hip_runtime.h>
#include <math.h>

#define H 8
#define B 64
#define D 512
#define EPS 1e-8f
#define INV_SQRT_D 0.04419417382415922f   // 1/sqrt(512)
#define LN2 0.6931471805599453f
#define EPS_LN2 6.931471805599453e-9f     // EPS * ln(2)
#define CUTOFF 34.0f                      // drop weights below 2^-34
#define TMAX_FALLBACK 36.0f               // flat softmax -> exact full scan
#define WIN 16                            // fixed half-window around insertion pt

__device__ __forceinline__ float fast_rcp(float x) { return __builtin_amdgcn_rcpf(x); }
__device__ __forceinline__ float fast_exp2(float x) { return __builtin_amdgcn_exp2f(x); }

// ---------------------------------------------------------------------------
// Fused kernel: one block per (h,b), 512 threads.
//  1. compute q,k,v for own column t
//  2. bitonic-sort (k, rowid) by k   -> lane t owns t-th smallest k
//  3. bitonic-sort (q, v) by q       -> published to LDS
//  4. binary-search own ki in sorted q (near-broadcast: lanes sorted by k)
//  5. fixed +/-WIN window accumulate (monotone p across wave -> coalesced LDS)
//  6. scatter result to ws_att[hb*D + rowid]
// Exactness: identical per-row math to the validated R8 kernel (absmax 0.0);
// full-scan fallback for flat-softmax rows keeps it data-independent.
// ---------------------------------------------------------------------------
__global__ __launch_bounds__(512, 2) void attn_sorted(
    const float* __restrict__ x,
    const float* __restrict__ Wq, const float* __restrict__ bq,
    const float* __restrict__ Wk, const float* __restrict__ bk,
    const float* __restrict__ Wv, const float* __restrict__ bv,
    float* __restrict__ ws_att)
{
    const int hb = blockIdx.x;          // 0..H*B-1
    const int h = hb >> 6;              // B == 64
    const int b = hb & 63;
    const int t = threadIdx.x;

    __shared__ __align__(16) float s0[D];
    __shared__ __align__(16) float s1[D];

    const float xv = x[b * D + t];
    float q  = fmaf(Wq[h * D + t], xv, bq[h * D + t]);
    float v  = fmaf(Wv[h * D + t], xv, bv[h * D + t]);
    float k  = fmaf(Wk[h * D + t], xv, bk[h * D + t]);
    float pay = __int_as_float(t);      // row id payload for the k-sort

    // --- Sort 1: (k, pay) ascending by k. j<=32 via shfl, j>=64 via LDS. ---
    for (int kk = 2; kk <= D; kk <<= 1) {
        const bool up = ((t & kk) == 0);
        for (int j = kk >> 1; j > 0; j >>= 1) {
            float kp, pp;
            if (j >= 64) {
                s0[t] = k; s1[t] = pay;
                __syncthreads();
                kp = s0[t ^ j]; pp = s1[t ^ j];
                __syncthreads();
            } else {
                kp = __shfl_xor(k, j, 64);
                pp = __shfl_xor(pay, j, 64);
            }
            const bool keepmin = (((t & j) == 0) == up);
            const bool take = keepmin ? (kp < k) : (kp > k);
            if (take) { k = kp; pay = pp; }
        }
    }

    // --- Sort 2: (q, v) ascending by q. ---
    for (int kk = 2; kk <= D; kk <<= 1) {
        const bool up = ((t & kk) == 0);
        for (int j = kk >> 1; j > 0; j >>= 1) {
            float qp, vp;
            if (j >= 64) {
                s0[t] = q; s1[t] = v;
                __syncthreads();
                qp = s0[t ^ j]; vp = s1[t ^ j];
                __syncthreads();
            } else {
                qp = __shfl_xor(q, j, 64);
                vp = __shfl_xor(v, j, 64);
            }
            const bool keepmin = (((t & j) == 0) == up);
            const bool take = keepmin ? (qp < q) : (qp > q);
            if (take) { q = qp; v = vp; }
        }
    }

    // Publish sorted (q,v)
    s0[t] = q; s1[t] = v;
    __syncthreads();

    const float ki = k;
    const int rid = __float_as_int(pay);

    // Binary search: p = count of s0[] < ki (10 uniform iterations)
    int lo = 0, hi = D;
    while (lo < hi) {
        const int mid = (lo + hi) >> 1;
        if (s0[mid] < ki) lo = mid + 1; else hi = mid;
    }
    const int p = lo;

    const float dlo = (p > 0) ? (ki - s0[p - 1]) : INFINITY;
    const float dhi = (p < D) ? (s0[p] - ki) : INFINITY;
    const float dmin = fmaxf(fminf(dlo, dhi), 0.f);
    const float tmax = fast_rcp(fmaf(dmin, LN2, EPS_LN2));

    float l = 0.f, a = 0.f;
    if (tmax < TMAX_FALLBACK) {
        // Flat softmax: exact full scan (broadcast reads; rare)
        for (int s = 0; s < D; ++s) {
            const float d = fabsf(s0[s] - ki);
            const float e = fast_exp2(fast_rcp(fmaf(d, LN2, EPS_LN2)) - tmax);
            l += e; a = fmaf(e, s1[s], a);
        }
    } else {
        // Fixed window [p-WIN, p+WIN): independent, near-coalesced LDS reads
        #pragma unroll 8
        for (int o = 0; o < 2 * WIN; ++o) {
            const int s = p - WIN + o;
            const bool valid = (s >= 0) && (s < D);
            const int sc = valid ? s : 0;
            const float d = fabsf(s0[sc] - ki);
            float e = fast_exp2(fast_rcp(fmaf(d, LN2, EPS_LN2)) - tmax);
            e = valid ? e : 0.f;
            l += e; a = fmaf(e, s1[sc], a);
        }
        // Exactness guards: extend while still within rad (rarely taken)
        const float rad = fast_rcp((tmax - CUTOFF) * LN2) * 1.001f;
        for (int s = p - WIN - 1; s >= 0; --s) {
            const float d = ki - s0[s];
            if (d > rad) break;
            const float e = fast_exp2(fast_rcp(fmaf(d, LN2, EPS_LN2)) - tmax);
            l += e; a = fmaf(e, s1[s], a);
        }
        for (int s = p + WIN; s < D; ++s) {
            const float d = s0[s] - ki;
            if (d > rad) break;
            const float e = fast_exp2(fast_rcp(fmaf(d, LN2, EPS_LN2)) - tmax);
            l += e; a = fmaf(e, s1[s], a);
        }
    }

    ws_att[hb * D + rid] = a * fast_rcp(l) * INV_SQRT_D;
}

// out[b,i] = x[b,i] + sum_h att[h,b,i]  (deterministic h-sum)
__global__ __launch_bounds__(256) void reduce_h(
    const float* __restrict__ x, const float* __restrict__ att,
    float* __restrict__ out)
{
    const int i = blockIdx.x * 256 + threadIdx.x;   // 0..B*D-1
    float s = x[i];
    #pragma unroll
    for (int h = 0; h < H; ++h) s += att[h * (B * D) + i];
    out[i] = s;
}

// ---------------------------------------------------------------------------
// Fallback (ws too small): fully fused exact kernel.
// ---------------------------------------------------------------------------
__global__ __launch_bounds__(512) void attn_fused(
    const float* __restrict__ x,
    const float* __restrict__ Wq, const float* __restrict__ bq,
    const float* __restrict__ Wk, const float* __restrict__ bk,
    const float* __restrict__ Wv, const float* __restrict__ bv,
    float* __restrict__ out)
{
    const int b = blockIdx.x;
    const int t = threadIdx.x;

    __shared__ float qs[D];
    __shared__ float vs[D];

    const float xv = x[b * D + t];
    float total = 0.f;

    for (int h = 0; h < H; ++h) {
        __syncthreads();
        qs[t] = Wq[h * D + t] * xv + bq[h * D + t];
        vs[t] = Wv[h * D + t] * xv + bv[h * D + t];
        const float ki = Wk[h * D + t] * xv + bk[h * D + t];
        __syncthreads();

        const float4* q4 = reinterpret_cast<const float4*>(qs);
        const float4* v4 = reinterpret_cast<const float4*>(vs);

        float d0 = INFINITY, d1 = INFINITY, d2 = INFINITY, d3 = INFINITY;
        for (int j = 0; j < D / 4; ++j) {
            float4 qq = q4[j];
            d0 = fminf(d0, fabsf(qq.x - ki));
            d1 = fminf(d1, fabsf(qq.y - ki));
            d2 = fminf(d2, fabsf(qq.z - ki));
            d3 = fminf(d3, fabsf(qq.w - ki));
        }
        const float dmin = fminf(fminf(d0, d1), fminf(d2, d3));
        const float tmax = fast_rcp(fmaf(dmin, LN2, EPS_LN2));

        float l0 = 0.f, l1 = 0.f, l2 = 0.f, l3 = 0.f;
        float a0 = 0.f, a1 = 0.f, a2 = 0.f, a3 = 0.f;
        for (int j = 0; j < D / 4; ++j) {
            float4 qq = q4[j];
            float4 vv = v4[j];
            float e0 = fast_exp2(fast_rcp(fmaf(fabsf(qq.x - ki), LN2, EPS_LN2)) - tmax);
            float e1 = fast_exp2(fast_rcp(fmaf(fabsf(qq.y - ki), LN2, EPS_LN2)) - tmax);
            float e2 = fast_exp2(fast_rcp(fmaf(fabsf(qq.z - ki), LN2, EPS_LN2)) - tmax);
            float e3 = fast_exp2(fast_rcp(fmaf(fabsf(qq.w - ki), LN2, EPS_LN2)) - tmax);
            l0 += e0; a0 = fmaf(e0, vv.x, a0);
            l1 += e1; a1 = fmaf(e1, vv.y, a1);
            l2 += e2; a2 = fmaf(e2, vv.z, a2);
            l3 += e3; a3 = fmaf(e3, vv.w, a3);
        }
        const float l = (l0 + l1) + (l2 + l3);
        const float a = (a0 + a1) + (a2 + a3);
        total += a * fast_rcp(l) * INV_SQRT_D;
    }
    out[b * D + t] = xv + total;
}

extern "C" void kernel_launch(void* const* d_in, const int* in_sizes, int n_in,
                              void* d_out, int out_size, void* d_ws, size_t ws_size,
                              hipStream_t stream) {
    const float* x  = (const float*)d_in[0];
    const float* Wq = (const float*)d_in[1];
    const float* bq = (const float*)d_in[2];
    const float* Wk = (const float*)d_in[3];
    const float* bk = (const float*)d_in[4];
    const float* Wv = (const float*)d_in[5];
    const float* bv = (const float*)d_in[6];
    float* out = (float*)d_out;

    const size_t need = (size_t)H * B * D * sizeof(float);   // 1 MB

    if (ws_size >= need) {
        float* ws = (float*)d_ws;
        attn_sorted<<<H * B, 512, 0, stream>>>(x, Wq, bq, Wk, bk, Wv, bv, ws);
        reduce_h<<<(B * D) / 256, 256, 0, stream>>>(x, ws, out);
    } else {
        attn_fused<<<B, 512, 0, stream>>>(x, Wq, bq, Wk, bk, Wv, bv, out);
    }
}

// Round 10
// 51.660 us; speedup vs baseline: 1.4169x; 1.0878x over previous
//
#include <hip/hip_runtime.h>
#include <math.h>

#define H 8
#define B 64
#define D 512
#define EPS 1e-8f
#define INV_SQRT_D 0.04419417382415922f   // 1/sqrt(512)
#define LN2 0.6931471805599453f
#define EPS_LN2 6.931471805599453e-9f     // EPS * ln(2)
#define CUTOFF 34.0f                      // drop weights below 2^-34
#define TMAX_FALLBACK 36.0f               // flat softmax -> rad=INF (full compute)

__device__ __forceinline__ float fast_rcp(float x) { return __builtin_amdgcn_rcpf(x); }
__device__ __forceinline__ float fast_exp2(float x) { return __builtin_amdgcn_exp2f(x); }

// ---------------------------------------------------------------------------
// One block per (h,b), 512 threads.
//  1. compute q,k,v for own column t
//  2. bitonic-sort (k, rowid) by k  -> lane t owns t-th smallest k; a wave's
//     64 k's span ~1/8 of the value range, so its active q-columns cluster.
//  3. publish q,v (ORIGINAL order) to LDS -- no q-sort, no binary search.
//  4. pass 1: brute dmin over all j (cheap: sub+min, float4 LDS reads)
//  5. pass 2: per float4 group, wave-uniform skip via __any(|d|<=rad);
//     body (rcp+exp2) only when some lane is within its window.
//     rad=INF for flat-softmax rows => they simply never skip (exact).
//  6. scatter result to ws_att[hb*D + rowid]
// Exact at fp32: skipped terms are < 2^-34 relative to a sum >= 1.
// ---------------------------------------------------------------------------
__global__ __launch_bounds__(512, 2) void attn_ksort(
    const float* __restrict__ x,
    const float* __restrict__ Wq, const float* __restrict__ bq,
    const float* __restrict__ Wk, const float* __restrict__ bk,
    const float* __restrict__ Wv, const float* __restrict__ bv,
    float* __restrict__ ws_att)
{
    const int hb = blockIdx.x;          // 0..H*B-1
    const int h = hb >> 6;              // B == 64
    const int b = hb & 63;
    const int t = threadIdx.x;

    __shared__ __align__(16) float s0[D];
    __shared__ __align__(16) float s1[D];

    const float xv = x[b * D + t];
    const float q = fmaf(Wq[h * D + t], xv, bq[h * D + t]);
    const float v = fmaf(Wv[h * D + t], xv, bv[h * D + t]);
    float k       = fmaf(Wk[h * D + t], xv, bk[h * D + t]);
    float pay = __int_as_float(t);      // row id payload

    // --- Bitonic sort (k, pay) ascending by k. j<=32 via shfl, j>=64 via LDS.
    for (int kk = 2; kk <= D; kk <<= 1) {
        const bool up = ((t & kk) == 0);
        for (int j = kk >> 1; j > 0; j >>= 1) {
            float kp, pp;
            if (j >= 64) {
                s0[t] = k; s1[t] = pay;
                __syncthreads();
                kp = s0[t ^ j]; pp = s1[t ^ j];
                __syncthreads();
            } else {
                kp = __shfl_xor(k, j, 64);
                pp = __shfl_xor(pay, j, 64);
            }
            const bool keepmin = (((t & j) == 0) == up);
            const bool take = keepmin ? (kp < k) : (kp > k);
            if (take) { k = kp; pay = pp; }
        }
    }

    // Publish q,v in ORIGINAL column order (sort scratch safely dead here)
    s0[t] = q; s1[t] = v;
    __syncthreads();

    const float ki = k;
    const int rid = __float_as_int(pay);

    const float4* q4 = reinterpret_cast<const float4*>(s0);
    const float4* v4 = reinterpret_cast<const float4*>(s1);

    // Pass 1: dmin = min_j |q_j - k_i|  (4 chains)
    float m0 = INFINITY, m1 = INFINITY, m2 = INFINITY, m3 = INFINITY;
    for (int j = 0; j < D / 4; ++j) {
        float4 qq = q4[j];
        m0 = fminf(m0, fabsf(qq.x - ki));
        m1 = fminf(m1, fabsf(qq.y - ki));
        m2 = fminf(m2, fabsf(qq.z - ki));
        m3 = fminf(m3, fabsf(qq.w - ki));
    }
    const float dmin = fminf(fminf(m0, m1), fminf(m2, m3));
    const float tmax = fast_rcp(fmaf(dmin, LN2, EPS_LN2));
    // Window radius; INF for flat rows (they compute every term -> exact)
    const float rad = (tmax < TMAX_FALLBACK)
                        ? INFINITY
                        : fast_rcp((tmax - CUTOFF) * LN2) * 1.001f;

    // Pass 2: skip-gated accumulation
    float l0 = 0.f, l1 = 0.f, a0 = 0.f, a1 = 0.f;
    for (int j = 0; j < D / 4; ++j) {
        float4 qq = q4[j];
        const float d0 = qq.x - ki;
        const float d1 = qq.y - ki;
        const float d2 = qq.z - ki;
        const float d3 = qq.w - ki;
        const bool c0 = fabsf(d0) <= rad;
        const bool c1 = fabsf(d1) <= rad;
        const bool c2 = fabsf(d2) <= rad;
        const bool c3 = fabsf(d3) <= rad;
        if (__any(c0 | c1 | c2 | c3)) {
            float4 vv = v4[j];
            const float e0 = c0 ? fast_exp2(fast_rcp(fmaf(fabsf(d0), LN2, EPS_LN2)) - tmax) : 0.f;
            const float e1 = c1 ? fast_exp2(fast_rcp(fmaf(fabsf(d1), LN2, EPS_LN2)) - tmax) : 0.f;
            const float e2 = c2 ? fast_exp2(fast_rcp(fmaf(fabsf(d2), LN2, EPS_LN2)) - tmax) : 0.f;
            const float e3 = c3 ? fast_exp2(fast_rcp(fmaf(fabsf(d3), LN2, EPS_LN2)) - tmax) : 0.f;
            l0 += e0; a0 = fmaf(e0, vv.x, a0);
            l1 += e1; a1 = fmaf(e1, vv.y, a1);
            l0 += e2; a0 = fmaf(e2, vv.z, a0);
            l1 += e3; a1 = fmaf(e3, vv.w, a1);
        }
    }
    const float l = l0 + l1;
    const float a = a0 + a1;

    ws_att[hb * D + rid] = a * fast_rcp(l) * INV_SQRT_D;
}

// out[b,i] = x[b,i] + sum_h att[h,b,i]  (deterministic h-sum)
__global__ __launch_bounds__(256) void reduce_h(
    const float* __restrict__ x, const float* __restrict__ att,
    float* __restrict__ out)
{
    const int i = blockIdx.x * 256 + threadIdx.x;   // 0..B*D-1
    float s = x[i];
    #pragma unroll
    for (int h = 0; h < H; ++h) s += att[h * (B * D) + i];
    out[i] = s;
}

// ---------------------------------------------------------------------------
// Fallback (ws too small): fully fused exact kernel.
// ---------------------------------------------------------------------------
__global__ __launch_bounds__(512) void attn_fused(
    const float* __restrict__ x,
    const float* __restrict__ Wq, const float* __restrict__ bq,
    const float* __restrict__ Wk, const float* __restrict__ bk,
    const float* __restrict__ Wv, const float* __restrict__ bv,
    float* __restrict__ out)
{
    const int b = blockIdx.x;
    const int t = threadIdx.x;

    __shared__ float qs[D];
    __shared__ float vs[D];

    const float xv = x[b * D + t];
    float total = 0.f;

    for (int h = 0; h < H; ++h) {
        __syncthreads();
        qs[t] = Wq[h * D + t] * xv + bq[h * D + t];
        vs[t] = Wv[h * D + t] * xv + bv[h * D + t];
        const float ki = Wk[h * D + t] * xv + bk[h * D + t];
        __syncthreads();

        const float4* q4 = reinterpret_cast<const float4*>(qs);
        const float4* v4 = reinterpret_cast<const float4*>(vs);

        float d0 = INFINITY, d1 = INFINITY, d2 = INFINITY, d3 = INFINITY;
        for (int j = 0; j < D / 4; ++j) {
            float4 qq = q4[j];
            d0 = fminf(d0, fabsf(qq.x - ki));
            d1 = fminf(d1, fabsf(qq.y - ki));
            d2 = fminf(d2, fabsf(qq.z - ki));
            d3 = fminf(d3, fabsf(qq.w - ki));
        }
        const float dmin = fminf(fminf(d0, d1), fminf(d2, d3));
        const float tmax = fast_rcp(fmaf(dmin, LN2, EPS_LN2));

        float l0 = 0.f, l1 = 0.f, l2 = 0.f, l3 = 0.f;
        float a0 = 0.f, a1 = 0.f, a2 = 0.f, a3 = 0.f;
        for (int j = 0; j < D / 4; ++j) {
            float4 qq = q4[j];
            float4 vv = v4[j];
            float e0 = fast_exp2(fast_rcp(fmaf(fabsf(qq.x - ki), LN2, EPS_LN2)) - tmax);
            float e1 = fast_exp2(fast_rcp(fmaf(fabsf(qq.y - ki), LN2, EPS_LN2)) - tmax);
            float e2 = fast_exp2(fast_rcp(fmaf(fabsf(qq.z - ki), LN2, EPS_LN2)) - tmax);
            float e3 = fast_exp2(fast_rcp(fmaf(fabsf(qq.w - ki), LN2, EPS_LN2)) - tmax);
            l0 += e0; a0 = fmaf(e0, vv.x, a0);
            l1 += e1; a1 = fmaf(e1, vv.y, a1);
            l2 += e2; a2 = fmaf(e2, vv.z, a2);
            l3 += e3; a3 = fmaf(e3, vv.w, a3);
        }
        const float l = (l0 + l1) + (l2 + l3);
        const float a = (a0 + a1) + (a2 + a3);
        total += a * fast_rcp(l) * INV_SQRT_D;
    }
    out[b * D + t] = xv + total;
}

extern "C" void kernel_launch(void* const* d_in, const int* in_sizes, int n_in,
                              void* d_out, int out_size, void* d_ws, size_t ws_size,
                              hipStream_t stream) {
    const float* x  = (const float*)d_in[0];
    const float* Wq = (const float*)d_in[1];
    const float* bq = (const float*)d_in[2];
    const float* Wk = (const float*)d_in[3];
    const float* bk = (const float*)d_in[4];
    const float* Wv = (const float*)d_in[5];
    const float* bv = (const float*)d_in[6];
    float* out = (float*)d_out;

    const size_t need = (size_t)H * B * D * sizeof(float);   // 1 MB

    if (ws_size >= need) {
        float* ws = (float*)d_ws;
        attn_ksort<<<H * B, 512, 0, stream>>>(x, Wq, bq, Wk, bk, Wv, bv, ws);
        reduce_h<<<(B * D) / 256, 256, 0, stream>>>(x, ws, out);
    } else {
        attn_fused<<<B, 512, 0, stream>>>(x, Wq, bq, Wk, bk, Wv, bv, out);
    }
}